// Round 3
// baseline (6294.570 us; speedup 1.0000x reference)
//
#include <hip/hip_runtime.h>
#include <math.h>

#define Bb 128
#define Tt 1024
#define Ff 128
#define Hh 256
#define Oo 128

#define NW 176u  // resident weight u32s per thread

// d_ws layout (u32 words)
#define OFF_PACK 0u
#define PACK_SZ  (2u * NW * 512u)          // 180224
#define OFF_FLAG (OFF_PACK + PACK_SZ)      // 256 flags
#define OFF_HX   (OFF_FLAG + 256u)         // 2 bufs * 256 blocks * 320 u32
#define HX_STRIDE 320u
#define OFF_PART (OFF_HX + 2u * 256u * HX_STRIDE)

typedef _Float16 half2_t __attribute__((ext_vector_type(2)));
union U32H2 { unsigned int u; half2_t h; };
union U32F { unsigned int u; float f; };

__device__ __forceinline__ float dot2f(unsigned int wu, unsigned int hu, float acc) {
    U32H2 a, b; a.u = wu; b.u = hu;
#if __has_builtin(__builtin_amdgcn_fdot2)
    return __builtin_amdgcn_fdot2(a.h, b.h, acc, false);
#else
    return acc + (float)a.h.x * (float)b.h.x + (float)a.h.y * (float)b.h.y;
#endif
}

// dst[(role*NW + j)*512 + tid]; thread key: d=tid&127, q=tid>>7
// j in [0,96)   : whh gate g=j>>5, k-u32 p=j&31 -> row g*256+role*128+d, k-u32 32q+p
// j in [96,144) : wih gate g=(j-96)>>4, p=(j-96)&15 -> row g*256+role*128+d, k-u32 16q+p
// j in [144,160): wsel row d, k-u32 (within role half) = q*16 + (j-144)
// j in [160,176): wout row d, k-u32 (within role half) = q*16 + (j-160)
__global__ void pack_kernel(const float* __restrict__ wih, const float* __restrict__ whh,
                            const float* __restrict__ wsel, const float* __restrict__ wout,
                            unsigned int* __restrict__ dst) {
    unsigned pid = blockIdx.x * 256 + threadIdx.x;
    if (pid >= 2u * NW * 512u) return;
    int tid = pid & 511;
    int j = (pid >> 9) % NW;
    int role = pid / (NW * 512u);
    int d = tid & 127, q = tid >> 7;
    const float* src; int idx0;
    if (j < 96) {
        int g = j >> 5, p = j & 31;
        int R = g * 256 + role * 128 + d;
        src = whh; idx0 = R * 256 + 2 * (32 * q + p);
    } else if (j < 144) {
        int jj = j - 96, g = jj >> 4, p = jj & 15;
        int R = g * 256 + role * 128 + d;
        src = wih; idx0 = R * 128 + 2 * (16 * q + p);
    } else if (j < 160) {
        int jj = j - 144;
        src = wsel; idx0 = d * 256 + role * 128 + 2 * (16 * q + jj);
    } else {
        int jj = j - 160;
        src = wout; idx0 = d * 256 + role * 128 + 2 * (16 * q + jj);
    }
    U32H2 v; v.h = (half2_t){ (_Float16)src[idx0], (_Float16)src[idx0 + 1] };
    dst[pid] = v.u;
}

__global__ void zero_flags(unsigned int* __restrict__ flags) {
    flags[threadIdx.x] = 0u;
}

__global__ __launch_bounds__(512, 2)
void gru_kernel(const float* __restrict__ x, const float* __restrict__ noise,
                const float* __restrict__ bih, const float* __restrict__ bhh,
                const float* __restrict__ bout, const float* __restrict__ bsel,
                unsigned int* __restrict__ wsu,
                float* __restrict__ outputs, float* __restrict__ selw,
                float* __restrict__ partials) {
    const int bid = blockIdx.x;
    const int row = bid & 127;
    const int role = bid >> 7;          // (row, row+128) pair -> same XCD
    const int tid = threadIdx.x;
    const int d = tid & 127, q = tid >> 7;

    __shared__ unsigned int h2u[128];   // full h as fp16 pairs
    __shared__ unsigned int wxu[64];    // gated input as fp16 pairs
    __shared__ float red[512 * 5];      // stride-5 padded partials

    // ---- resident weights -> registers, pinned so they cannot be rematerialized ----
    unsigned int whh2[96], wih2[48], wsel2[16], wout2[16];
    const unsigned int base = (unsigned)(role * NW) * 512u + (unsigned)tid;
    const unsigned int* __restrict__ pk = wsu + OFF_PACK;
    #pragma unroll
    for (int j = 0; j < 96; j++) whh2[j] = pk[base + j * 512];
    #pragma unroll
    for (int j = 0; j < 48; j++) wih2[j] = pk[base + (96 + j) * 512];
    #pragma unroll
    for (int j = 0; j < 16; j++) wsel2[j] = pk[base + (144 + j) * 512];
    #pragma unroll
    for (int j = 0; j < 16; j++) wout2[j] = pk[base + (160 + j) * 512];
    #pragma unroll
    for (int j = 0; j < 96; j++) asm volatile("" : "+v"(whh2[j]));
    #pragma unroll
    for (int j = 0; j < 48; j++) asm volatile("" : "+v"(wih2[j]));
    #pragma unroll
    for (int j = 0; j < 16; j++) asm volatile("" : "+v"(wsel2[j]));
    #pragma unroll
    for (int j = 0; j < 16; j++) asm volatile("" : "+v"(wout2[j]));

    // ---- biases ----
    float bias_r = 0.f, bias_z = 0.f, bias_in = 0.f, bias_hn = 0.f, bsel_d = 0.f, bout_o = 0.f;
    if (tid < 128) {
        int gr = role * 128 + d;
        bias_r  = bih[gr]       + bhh[gr];
        bias_z  = bih[256 + gr] + bhh[256 + gr];
        bias_in = bih[512 + gr];
        bias_hn = bhh[512 + gr];
        bsel_d  = bsel[d];
    } else if (tid < 256) {
        bout_o = bout[tid - 128];
    }

    // ---- init ----
    if (tid < 128) {
        h2u[tid] = 0u;
        float x0 = x[(size_t)row * Tt * Ff + tid];
        float xp = __shfl_xor(x0, 1, 64);
        if (!(tid & 1)) {
            U32H2 v; v.h = (half2_t){ (_Float16)x0, (_Float16)xp };
            wxu[tid >> 1] = v.u;
        }
        if (role == 0) selw[(size_t)row * Ff + tid] = 1.0f;
    }
    __syncthreads();

    unsigned int* flags = wsu + OFF_FLAG;
    unsigned int* hx    = wsu + OFF_HX;
    unsigned int* myflag = &flags[row * 2 + role];
    unsigned int* pflag  = &flags[row * 2 + (role ^ 1)];

    float h_old = 0.f, ssum = 0.f;
    size_t xbase  = ((size_t)row * Tt + 1) * Ff + d;
    size_t nzbase = (size_t)row * Ff + d;
    size_t swbase = ((size_t)Bb + row) * Ff + d;
    size_t obase  = (size_t)row * Oo + ((tid >= 128 && tid < 256) ? (tid - 128) : 0);

    const uint4* h4 = (const uint4*)h2u;
    const uint4* w4 = (const uint4*)wxu;

    for (int t = 0; t < Tt; ++t) {
        const unsigned mb_my = ((unsigned)(t & 1) * 256u + (unsigned)(row * 2 + role)) * HX_STRIDE;
        const unsigned mb_p  = ((unsigned)(t & 1) * 256u + (unsigned)(row * 2 + (role ^ 1))) * HX_STRIDE;

        // prefetch next-step inputs (consumed in finalize; hides HBM latency under G)
        float xv = 0.f, nzv = 0.f;
        if (tid < 128 && t < Tt - 1) { xv = x[xbase]; nzv = noise[nzbase]; }

        // ---- G: gate partials over full h (own 384 gate rows, own k-quarter) ----
        float a_r = 0.f, a_z = 0.f, a_in = 0.f, a_hn = 0.f;
        #pragma unroll
        for (int pp = 0; pp < 8; ++pp) {
            uint4 hv = h4[8 * q + pp];
            unsigned hh[4] = { hv.x, hv.y, hv.z, hv.w };
            #pragma unroll
            for (int i = 0; i < 4; i++) {
                a_r  = dot2f(whh2[pp * 4 + i],      hh[i], a_r);
                a_z  = dot2f(whh2[32 + pp * 4 + i], hh[i], a_z);
                a_hn = dot2f(whh2[64 + pp * 4 + i], hh[i], a_hn);
            }
        }
        #pragma unroll
        for (int pp = 0; pp < 4; ++pp) {
            uint4 wv = w4[4 * q + pp];
            unsigned ww[4] = { wv.x, wv.y, wv.z, wv.w };
            #pragma unroll
            for (int i = 0; i < 4; i++) {
                a_r  = dot2f(wih2[pp * 4 + i],      ww[i], a_r);
                a_z  = dot2f(wih2[16 + pp * 4 + i], ww[i], a_z);
                a_in = dot2f(wih2[32 + pp * 4 + i], ww[i], a_in);
            }
        }
        red[tid * 5 + 0] = a_r; red[tid * 5 + 1] = a_z;
        red[tid * 5 + 2] = a_in; red[tid * 5 + 3] = a_hn;
        __syncthreads();                                   // B1

        // ---- H: finalize own h-half; pack + publish h ----
        if (tid < 128) {
            float rr = bias_r, zz = bias_z, ii = bias_in, hh = bias_hn;
            #pragma unroll
            for (int qq = 0; qq < 4; qq++) {
                int b0 = (qq * 128 + d) * 5;
                rr += red[b0]; zz += red[b0 + 1]; ii += red[b0 + 2]; hh += red[b0 + 3];
            }
            float r = 1.f / (1.f + expf(-rr));
            float z = 1.f / (1.f + expf(-zz));
            float n = tanhf(ii + r * hh);
            float hn2 = (1.f - z) * n + z * h_old;
            h_old = hn2;
            float hp = __shfl_xor(hn2, 1, 64);
            if (!(d & 1)) {
                U32H2 v; v.h = (half2_t){ (_Float16)hn2, (_Float16)hp };
                h2u[role * 64 + (d >> 1)] = v.u;
                __hip_atomic_store(&hx[mb_my + (d >> 1)], v.u,
                                   __ATOMIC_RELAXED, __HIP_MEMORY_SCOPE_AGENT);
            }
        }
        __syncthreads();                                   // B2

        // ---- P: sel/out partials over OWN h-half (k-split by role) ----
        float s_acc = 0.f, o_acc = 0.f;
        #pragma unroll
        for (int pp = 0; pp < 4; ++pp) {
            uint4 hv = h4[role * 16 + q * 4 + pp];
            unsigned hh2[4] = { hv.x, hv.y, hv.z, hv.w };
            #pragma unroll
            for (int i = 0; i < 4; i++) {
                s_acc = dot2f(wsel2[pp * 4 + i], hh2[i], s_acc);
                o_acc = dot2f(wout2[pp * 4 + i], hh2[i], o_acc);
            }
        }
        red[tid * 5 + 0] = s_acc; red[tid * 5 + 1] = o_acc;
        __syncthreads();                                   // B3

        float own_s = 0.f, own_o = 0.f;
        if (tid < 128) {
            #pragma unroll
            for (int qq = 0; qq < 4; qq++) own_s += red[(qq * 128 + d) * 5 + 0];
            U32F u; u.f = own_s;
            __hip_atomic_store(&hx[mb_my + 64 + d], u.u,
                               __ATOMIC_RELAXED, __HIP_MEMORY_SCOPE_AGENT);
        } else if (tid < 256) {
            int r2 = tid - 128;
            #pragma unroll
            for (int qq = 0; qq < 4; qq++) own_o += red[(qq * 128 + r2) * 5 + 1];
            U32F u; u.f = own_o;
            __hip_atomic_store(&hx[mb_my + 192 + r2], u.u,
                               __ATOMIC_RELAXED, __HIP_MEMORY_SCOPE_AGENT);
        }
        __syncthreads();                                   // B4 (drains mailbox stores)

        if (tid == 0) {
            __hip_atomic_store(myflag, (unsigned)(t + 1), __ATOMIC_RELEASE, __HIP_MEMORY_SCOPE_AGENT);
            while (__hip_atomic_load(pflag, __ATOMIC_ACQUIRE, __HIP_MEMORY_SCOPE_AGENT) < (unsigned)(t + 1))
                __builtin_amdgcn_s_sleep(1);
        }
        __syncthreads();                                   // B5

        // ---- finalize: merge partner partials; produce w, wx, outputs; fill partner h ----
        if (tid < 64) {
            unsigned pv = __hip_atomic_load(&hx[mb_p + tid],
                                            __ATOMIC_RELAXED, __HIP_MEMORY_SCOPE_AGENT);
            h2u[(role ^ 1) * 64 + tid] = pv;
        }
        if (tid < 128) {
            if (t < Tt - 1) {
                U32F ps; ps.u = __hip_atomic_load(&hx[mb_p + 64 + d],
                                                  __ATOMIC_RELAXED, __HIP_MEMORY_SCOPE_AGENT);
                float lg = bsel_d + own_s + ps.f;
                float arg = (lg + logf(nzv + 1e-20f) - logf(1.f - nzv + 1e-20f)) * 20.0f;
                float w = 1.f / (1.f + expf(-arg));
                if (role == 0) { selw[swbase] = w; ssum += w; }
                float wxv = w * xv;
                float wp = __shfl_xor(wxv, 1, 64);
                if (!(d & 1)) {
                    U32H2 v; v.h = (half2_t){ (_Float16)wxv, (_Float16)wp };
                    wxu[d >> 1] = v.u;
                }
            }
        } else if (tid < 256) {
            int r2 = tid - 128;
            U32F po; po.u = __hip_atomic_load(&hx[mb_p + 192 + r2],
                                              __ATOMIC_RELAXED, __HIP_MEMORY_SCOPE_AGENT);
            if ((r2 >> 6) == role) outputs[obase] = bout_o + own_o + po.f;
        }
        __syncthreads();                                   // B6

        obase += (size_t)Bb * Oo; nzbase += (size_t)Bb * Ff;
        swbase += (size_t)Bb * Ff; xbase += Ff;
    }

    // ---- per-row selection-sum partial (role 0 only) ----
    if (role == 0) {
        red[tid] = (tid < 128) ? ssum : 0.f;
        __syncthreads();
        for (int s = 256; s > 0; s >>= 1) {
            if (tid < s) red[tid] += red[tid + s];
            __syncthreads();
        }
        if (tid == 0) partials[row] = red[0];
    }
}

__global__ void finalize_kernel(const float* __restrict__ partials, float* __restrict__ out_scalar) {
    __shared__ float red[128];
    int t = threadIdx.x;
    red[t] = partials[t];
    __syncthreads();
    for (int s = 64; s > 0; s >>= 1) {
        if (t < s) red[t] += red[t + s];
        __syncthreads();
    }
    if (t == 0) out_scalar[0] = red[0];
}

extern "C" void kernel_launch(void* const* d_in, const int* in_sizes, int n_in,
                              void* d_out, int out_size, void* d_ws, size_t ws_size,
                              hipStream_t stream) {
    const float* x     = (const float*)d_in[0];
    const float* noise = (const float*)d_in[1];
    const float* w_ih  = (const float*)d_in[2];
    const float* w_hh  = (const float*)d_in[3];
    const float* b_ih  = (const float*)d_in[4];
    const float* b_hh  = (const float*)d_in[5];
    const float* W_out = (const float*)d_in[6];
    const float* b_out = (const float*)d_in[7];
    const float* W_sel = (const float*)d_in[8];
    const float* b_sel = (const float*)d_in[9];

    unsigned int* wsu = (unsigned int*)d_ws;
    float* out = (float*)d_out;
    float* outputs = out;                               // [T,B,O]
    float* nsel    = out + (size_t)Tt * Bb * Oo;        // scalar
    float* selw    = nsel + 1;                          // [T,B,F]
    float* partials = (float*)(wsu + OFF_PART);

    pack_kernel<<<(2 * NW * 512 + 255) / 256, 256, 0, stream>>>(w_ih, w_hh, W_sel, W_out, wsu + OFF_PACK);
    zero_flags<<<1, 256, 0, stream>>>(wsu + OFF_FLAG);
    gru_kernel<<<256, 512, 0, stream>>>(x, noise, b_ih, b_hh, b_out, b_sel,
                                        wsu, outputs, selw, partials);
    finalize_kernel<<<1, 128, 0, stream>>>(partials, nsel);
}